// Round 12
// baseline (87.402 us; speedup 1.0000x reference)
//
#include <hip/hip_runtime.h>

#define N_  128
#define C_  256
#define T_  48
#define V_  25

typedef float v4f __attribute__((ext_vector_type(4)));

// ---- K1: row means. Pure HBM read stream; leaves x L3-resident for K2. ----
// Block = 256 consecutive (n,c,t) rows of 25 floats = 25.6 KB contiguous.
__global__ __launch_bounds__(256) void k_rowmean(const float* __restrict__ x,
                                                 float* __restrict__ xbar) {
    __shared__ float xs[6400];
    const int tid = threadIdx.x;
    const float4* x4 = (const float4*)x;
    const unsigned base4 = blockIdx.x * 1600u;
    #pragma unroll
    for (int k = 0; k < 7; ++k) {
        int i4 = k * 256 + tid;
        if (i4 < 1600) ((float4*)xs)[i4] = x4[base4 + i4];
    }
    __syncthreads();
    float s = 0.f;
    #pragma unroll
    for (int v = 0; v < 25; ++v) s += xs[tid * 25 + v];   // stride 25: conflict-free
    xbar[blockIdx.x * 256u + tid] = s * 0.04f;            // mean (1/25 here)
}

// ---- K2: gate math (prologue) + apply (stream). Block = (n, quad of 4 segs). ----
__global__ __launch_bounds__(512, 4) void k_gateapply(
    const float* __restrict__ x, const float* __restrict__ xbar,
    const float* __restrict__ wsq, const float* __restrict__ bsq,
    const float* __restrict__ gamma, const float* __restrict__ beta,
    const float* __restrict__ rmean, const float* __restrict__ rvar,
    const float* __restrict__ wc1, const float* __restrict__ bc1,
    const float* __restrict__ wex, const float* __restrict__ bex,
    float* __restrict__ out)
{
    __shared__ float xm[12 * 256];    // means [t][c]        12,288 B
    __shared__ float wsqL[256 * 17];  // wsq transposed [c][r], stride 17
    __shared__ float gs[256 * 12];    // gate [c][t]         12,288 B
    __shared__ float part[384];       // [t][r][h]
    __shared__ float ybn[192], y1[192], mv[192];

    const int tid = threadIdx.x;
    const unsigned bid = blockIdx.x;
    const unsigned o  = (bid & 7u) * 64u + (bid >> 3);    // bijective XCD chunk swizzle
    const unsigned n  = o >> 2;
    const unsigned qd = o & 3u;

    // ---- load xbar slice [256c][12t] + wsq -> LDS ----
    for (int j = tid; j < 3072; j += 512) {
        int c = j / 12, t = j - c * 12;                   // 12-float runs, coalesced
        xm[t * 256 + c] = xbar[(unsigned)((n * 256u + c) * 48u + qd * 12u + t)];
    }
    #pragma unroll
    for (int it = 0; it < 8; ++it) {                      // 4096 floats
        int j = it * 512 + tid;
        int r = j >> 8, c = j & 255;
        wsqL[c * 17 + r] = wsq[j];
    }
    __syncthreads();

    // ---- B1: squeeze partials: (t, r, half), 128 MACs each ----
    if (tid < 384) {
        int t = tid >> 5, rh = tid & 31, r = rh >> 1, h = rh & 1;
        float acc = 0.f;
        #pragma unroll 8
        for (int i = 0; i < 128; ++i)
            acc += xm[t * 256 + h * 128 + i] * wsqL[(h * 128 + i) * 17 + r];
        part[tid] = acc;
    }
    __syncthreads();
    // ---- B1b: combine + BN (bsq folded) ----
    if (tid < 192) {
        int t = tid >> 4, r = tid & 15;
        float acc = part[t * 32 + r * 2] + part[t * 32 + r * 2 + 1];
        float sc = gamma[r] * rsqrtf(rvar[r] + 1e-5f);
        ybn[t * 16 + r] = (acc + bsq[r]) * sc + (beta[r] - rmean[r] * sc);
    }
    __syncthreads();
    // ---- B2: conv1 ----
    if (tid < 192) {
        int t = tid >> 4, s = tid & 15;
        float acc = bc1[s];
        #pragma unroll
        for (int r = 0; r < 16; ++r) acc += ybn[t * 16 + r] * wc1[s * 16 + r];
        y1[t * 16 + s] = acc;
    }
    __syncthreads();
    // ---- B3: temporal diff (quad = 4 whole segments) ----
    if (tid < 192) {
        int t = tid >> 4, r = tid & 15;
        mv[tid] = ((t % 3) < 2) ? (y1[(t + 1) * 16 + r] - ybn[t * 16 + r]) : 0.f;
    }
    __syncthreads();
    // ---- B4: expand + sigmoid: (c, t-half) ----
    {
        int c = tid & 255, half = tid >> 8;
        float wexr[16];
        #pragma unroll
        for (int r = 0; r < 16; ++r) wexr[r] = wex[c * 16 + r];
        float be = bex[c];
        #pragma unroll
        for (int t = half * 6; t < half * 6 + 6; ++t) {
            float a = be;
            #pragma unroll
            for (int r = 0; r < 16; ++r) a += mv[t * 16 + r] * wexr[r];
            gs[c * 12 + t] = 1.f / (1.f + expf(-a));
        }
    }
    __syncthreads();

    // ---- apply: x re-read (L3-warm from K1) * gate -> NT float4 store ----
    const v4f* x4 = (const v4f*)x + (size_t)n * 76800u + qd * 75u;   // + c*300 + k
    v4f*       o4 = (v4f*)out     + (size_t)n * 76800u + qd * 75u;
    #pragma unroll 4
    for (int it = 0; it < 38; ++it) {
        int j = it * 512 + tid;
        if (j < 19200) {
            unsigned c = ((unsigned)j * 55926u) >> 22;    // j/75 (exact for j<19200)
            int k = j - (int)c * 75;
            v4f v = x4[c * 300 + k];
            int m0  = k * 4;
            int t0  = (m0 * 41) >> 10;                    // m0/25 (exact m0<1024)
            int t3  = ((m0 + 3) * 41) >> 10;
            int rem = m0 - t0 * 25;
            float g0 = gs[c * 12 + t0];
            float g3 = gs[c * 12 + t3];
            v4f ov;
            ov.x = v.x * g0;
            ov.y = v.y * ((rem + 1 < 25) ? g0 : g3);
            ov.z = v.z * ((rem + 2 < 25) ? g0 : g3);
            ov.w = v.w * ((rem + 3 < 25) ? g0 : g3);
            __builtin_nontemporal_store(ov, &o4[c * 300 + k]);
        }
    }
}

extern "C" void kernel_launch(void* const* d_in, const int* in_sizes, int n_in,
                              void* d_out, int out_size, void* d_ws, size_t ws_size,
                              hipStream_t stream) {
    const float* x     = (const float*)d_in[0];
    const float* wsq   = (const float*)d_in[1];
    const float* bsq   = (const float*)d_in[2];
    const float* gamma = (const float*)d_in[3];
    const float* beta  = (const float*)d_in[4];
    const float* rmean = (const float*)d_in[5];
    const float* rvar  = (const float*)d_in[6];
    const float* wc1   = (const float*)d_in[7];
    const float* bc1   = (const float*)d_in[8];
    const float* wex   = (const float*)d_in[9];
    const float* bex   = (const float*)d_in[10];

    float* xbar = (float*)d_ws;                       // N*C*T floats = 6.29 MB

    k_rowmean<<<6144, 256, 0, stream>>>(x, xbar);
    k_gateapply<<<512, 512, 0, stream>>>(x, xbar, wsq, bsq, gamma, beta,
                                         rmean, rvar, wc1, bc1, wex, bex,
                                         (float*)d_out);
}